// Round 1
// baseline (802.076 us; speedup 1.0000x reference)
//
#include <hip/hip_runtime.h>

// Problem constants (from reference)
#define N_NODES  50000
#define N_EDGES  800000
#define S_SAMP   4
#define D_INF    96
#define D_HF     32
#define D_NOISE  32
#define D_OUTF   128
#define F_PACK   256   // X(96) | h(32) | eps0..3 (4*32)

#define GEMM_BLOCKS 256

// feature f in packed order -> source array element
__device__ __forceinline__ float load_feat(int f, int node,
    const float* __restrict__ X, const float* __restrict__ h,
    const float* __restrict__ eps) {
  if (f < 96)  return X[node * 96 + f];
  if (f < 128) return h[node * 32 + (f - 96)];
  int t = f - 128;
  int s = t >> 5, k = t & 31;
  return eps[((long)s * N_NODES + node) * 32 + k];
}

// ---- CSR build -------------------------------------------------------------
__global__ void k_hist(const int* __restrict__ dst, int* __restrict__ cnt) {
  int i = blockIdx.x * blockDim.x + threadIdx.x;
  if (i < N_EDGES) atomicAdd(&cnt[dst[i]], 1);
}

__global__ void k_scan(const int* __restrict__ cnt, int* __restrict__ off,
                       int* __restrict__ cursor) {
  __shared__ int sdata[256];
  __shared__ int carry;
  int tid = threadIdx.x;
  if (tid == 0) carry = 0;
  __syncthreads();
  for (int base = 0; base < N_NODES; base += 256) {
    int i = base + tid;
    int vIn = (i < N_NODES) ? cnt[i] : 0;
    sdata[tid] = vIn;
    __syncthreads();
    for (int d = 1; d < 256; d <<= 1) {
      int t = (tid >= d) ? sdata[tid - d] : 0;
      __syncthreads();
      sdata[tid] += t;
      __syncthreads();
    }
    int incl = sdata[tid];
    int cv = carry;
    if (i < N_NODES) {
      int e = cv + incl - vIn;
      off[i] = e;
      cursor[i] = e;
    }
    __syncthreads();
    if (tid == 255) carry = cv + incl;
    __syncthreads();
  }
  if (tid == 0) off[N_NODES] = carry;
}

__global__ void k_scatter(const int* __restrict__ src, const int* __restrict__ dst,
                          int* __restrict__ cursor, int* __restrict__ csr) {
  int i = blockIdx.x * blockDim.x + threadIdx.x;
  if (i < N_EDGES) {
    int pos = atomicAdd(&cursor[dst[i]], 1);
    csr[pos] = src[i];
  }
}

// ---- aggregation: one wave per node, lane = feature (+64*j) ---------------
__global__ void k_agg(const float* __restrict__ X, const float* __restrict__ h,
                      const float* __restrict__ eps, const float* __restrict__ geps_p,
                      const int* __restrict__ off, const int* __restrict__ csr,
                      float* __restrict__ agg) {
  int wave = (blockIdx.x * blockDim.x + threadIdx.x) >> 6;
  int lane = threadIdx.x & 63;
  if (wave >= N_NODES) return;
  int n = wave;
  float ge = 1.0f + geps_p[0];
  float acc0 = ge * load_feat(lane,       n, X, h, eps);
  float acc1 = ge * load_feat(lane + 64,  n, X, h, eps);
  float acc2 = ge * load_feat(lane + 128, n, X, h, eps);
  float acc3 = ge * load_feat(lane + 192, n, X, h, eps);
  int e0 = off[n], e1 = off[n + 1];
  for (int e = e0; e < e1; ++e) {
    int s = csr[e];
    acc0 += load_feat(lane,       s, X, h, eps);
    acc1 += load_feat(lane + 64,  s, X, h, eps);
    acc2 += load_feat(lane + 128, s, X, h, eps);
    acc3 += load_feat(lane + 192, s, X, h, eps);
  }
  float* ar = agg + (long)n * F_PACK;
  ar[lane]       = acc0;
  ar[lane + 64]  = acc1;
  ar[lane + 128] = acc2;
  ar[lane + 192] = acc3;
}

// ---- fused GEMM + ReLU + per-block node-sum --------------------------------
// thread: og = tid&31 owns o = og*4..og*4+3 ; slot = tid>>5 owns 4 nodes.
// agg row values are broadcast loads (same addr within half-wave), W float4 coalesced.
__global__ void k_gemm(const float* __restrict__ agg, const float* __restrict__ W,
                       const float* __restrict__ b, float* __restrict__ partials) {
  int tid = threadIdx.x;
  int og = tid & 31;
  int slot = tid >> 5;
  float psum[4][4];
#pragma unroll
  for (int s = 0; s < 4; ++s)
#pragma unroll
    for (int j = 0; j < 4; ++j) psum[s][j] = 0.f;
  const float4 bv = *(const float4*)(b + og * 4);

  const int ngroups = (N_NODES + 31) / 32;
  for (int grp = blockIdx.x; grp < ngroups; grp += gridDim.x) {
    int nbase = grp * 32 + slot * 4;
    int nn[4]; bool v[4];
#pragma unroll
    for (int ni = 0; ni < 4; ++ni) { nn[ni] = nbase + ni; v[ni] = nn[ni] < N_NODES; }

    float zsh[4][4];
#pragma unroll
    for (int ni = 0; ni < 4; ++ni)
#pragma unroll
      for (int j = 0; j < 4; ++j) zsh[ni][j] = 0.f;

    // shared part: packed k 0..127 -> W rows k (X) / k+32 (h)
#pragma unroll 4
    for (int k = 0; k < 128; ++k) {
      int wr = (k < 96) ? k : k + 32;
      float4 w = *(const float4*)(W + wr * D_OUTF + og * 4);
#pragma unroll
      for (int ni = 0; ni < 4; ++ni) {
        float a = v[ni] ? agg[(long)nn[ni] * F_PACK + k] : 0.f;
        zsh[ni][0] += a * w.x; zsh[ni][1] += a * w.y;
        zsh[ni][2] += a * w.z; zsh[ni][3] += a * w.w;
      }
    }
    // per-sample eps part: W rows 96..127
#pragma unroll
    for (int s = 0; s < 4; ++s) {
      float ze[4][4];
#pragma unroll
      for (int ni = 0; ni < 4; ++ni)
#pragma unroll
        for (int j = 0; j < 4; ++j) ze[ni][j] = 0.f;
#pragma unroll 4
      for (int k = 0; k < 32; ++k) {
        float4 w = *(const float4*)(W + (96 + k) * D_OUTF + og * 4);
#pragma unroll
        for (int ni = 0; ni < 4; ++ni) {
          float a = v[ni] ? agg[(long)nn[ni] * F_PACK + 128 + s * 32 + k] : 0.f;
          ze[ni][0] += a * w.x; ze[ni][1] += a * w.y;
          ze[ni][2] += a * w.z; ze[ni][3] += a * w.w;
        }
      }
#pragma unroll
      for (int ni = 0; ni < 4; ++ni) {
        float y0 = fmaxf(zsh[ni][0] + ze[ni][0] + bv.x, 0.f);
        float y1 = fmaxf(zsh[ni][1] + ze[ni][1] + bv.y, 0.f);
        float y2 = fmaxf(zsh[ni][2] + ze[ni][2] + bv.z, 0.f);
        float y3 = fmaxf(zsh[ni][3] + ze[ni][3] + bv.w, 0.f);
        if (v[ni]) { psum[s][0] += y0; psum[s][1] += y1; psum[s][2] += y2; psum[s][3] += y3; }
      }
    }
  }

  // reduce 8 slots -> one 512-vector per block
  __shared__ float red[8 * 512];
#pragma unroll
  for (int s = 0; s < 4; ++s)
#pragma unroll
    for (int j = 0; j < 4; ++j)
      red[slot * 512 + s * 128 + og * 4 + j] = psum[s][j];
  __syncthreads();
  for (int idx = tid; idx < 512; idx += 256) {
    float t = 0.f;
    for (int sl = 0; sl < 8; ++sl) t += red[sl * 512 + idx];
    partials[blockIdx.x * 512 + idx] = t;
  }
}

__global__ void k_reduce(const float* __restrict__ partials, float* __restrict__ means) {
  int idx = threadIdx.x;  // 512 threads
  float t = 0.f;
  for (int blk = 0; blk < GEMM_BLOCKS; ++blk) t += partials[blk * 512 + idx];
  float m = t * (1.0f / (float)N_NODES);
  means[idx] = fmaxf(m, 0.f);   // outer relu (no-op numerically, kept for exactness)
}

// ---- broadcast output + epsilon passthrough (float4) -----------------------
#define OUT0_F4 6400000L   // S*N*128/4
#define EPS_F4  1600000L   // S*N*32/4
__global__ void k_out(const float* __restrict__ means, const float* __restrict__ eps,
                      float* __restrict__ out) {
  long i = (long)blockIdx.x * blockDim.x + threadIdx.x;
  if (i < OUT0_F4) {
    int o4 = (int)(i & 31);
    long sn = i >> 5;
    int s = (int)(sn / N_NODES);
    ((float4*)out)[i] = ((const float4*)means)[s * 32 + o4];
  } else if (i < OUT0_F4 + EPS_F4) {
    long j = i - OUT0_F4;
    ((float4*)out)[OUT0_F4 + j] = ((const float4*)eps)[j];
  }
}

extern "C" void kernel_launch(void* const* d_in, const int* in_sizes, int n_in,
                              void* d_out, int out_size, void* d_ws, size_t ws_size,
                              hipStream_t stream) {
  const float* X    = (const float*)d_in[0];
  const float* h    = (const float*)d_in[1];
  const float* eps  = (const float*)d_in[2];
  const float* W    = (const float*)d_in[3];
  const float* b    = (const float*)d_in[4];
  const float* geps = (const float*)d_in[5];
  const int*   src  = (const int*)d_in[6];
  const int*   dst  = (const int*)d_in[7];
  float* out = (float*)d_out;

  char* w = (char*)d_ws;
  float* agg      = (float*)w; w += (size_t)N_NODES * F_PACK * 4;   // 51.2 MB
  int*   off      = (int*)w;   w += (size_t)(N_NODES + 16) * 4;
  int*   cnt      = (int*)w;   w += (size_t)N_NODES * 4;
  int*   cursor   = (int*)w;   w += (size_t)N_NODES * 4;
  int*   csr      = (int*)w;   w += (size_t)N_EDGES * 4;
  float* partials = (float*)w; w += (size_t)GEMM_BLOCKS * 512 * 4;
  float* means    = (float*)w; w += 512 * 4;

  hipMemsetAsync(cnt, 0, (size_t)N_NODES * 4, stream);

  int eb = (N_EDGES + 255) / 256;
  k_hist<<<eb, 256, 0, stream>>>(dst, cnt);
  k_scan<<<1, 256, 0, stream>>>(cnt, off, cursor);
  k_scatter<<<eb, 256, 0, stream>>>(src, dst, cursor, csr);

  k_agg<<<(N_NODES + 3) / 4, 256, 0, stream>>>(X, h, eps, geps, off, csr, agg);

  k_gemm<<<GEMM_BLOCKS, 256, 0, stream>>>(agg, W, b, partials);
  k_reduce<<<1, 512, 0, stream>>>(partials, means);

  long total_f4 = OUT0_F4 + EPS_F4;
  k_out<<<(int)((total_f4 + 255) / 256), 256, 0, stream>>>(means, eps, out);
}

// Round 2
// 422.780 us; speedup vs baseline: 1.8971x; 1.8971x over previous
//
#include <hip/hip_runtime.h>

#define N_NODES  50000
#define N_EDGES  800000
#define D_OUTF   128
#define F_PACK   256          // X(96) | h(32) | eps0..3 (4*32)
#define NTILES   3125         // 50000 / 16, exact
#define GEMM_BLOCKS 512

typedef __attribute__((ext_vector_type(8))) short bf16x8;
typedef __attribute__((ext_vector_type(4))) float f32x4;

__device__ __forceinline__ unsigned short f2bf(float x) {
  unsigned int u = __float_as_uint(x);
  u += 0x7FFFu + ((u >> 16) & 1u);           // RNE
  return (unsigned short)(u >> 16);
}
__device__ __forceinline__ float bflo(unsigned int u) { return __uint_as_float(u << 16); }
__device__ __forceinline__ float bfhi(unsigned int u) { return __uint_as_float(u & 0xFFFF0000u); }

// packed feature f -> source element
__device__ __forceinline__ float load_feat(int f, int node,
    const float* __restrict__ X, const float* __restrict__ h,
    const float* __restrict__ eps) {
  if (f < 96)  return X[node * 96 + f];
  if (f < 128) return h[node * 32 + (f - 96)];
  int t = f - 128;
  int s = t >> 5, k = t & 31;
  return eps[((long)s * N_NODES + node) * 32 + k];
}

// ---- pack features to bf16 [node][256] ------------------------------------
__global__ void k_pack(const float* __restrict__ X, const float* __restrict__ h,
                       const float* __restrict__ eps, unsigned short* __restrict__ feat) {
  int t = blockIdx.x * blockDim.x + threadIdx.x;   // one thread per (node, k-pair)
  if (t >= N_NODES * 128) return;
  int node = t >> 7, kk = (t & 127) << 1;
  float a = load_feat(kk, node, X, h, eps);
  float c = load_feat(kk + 1, node, X, h, eps);
  ((unsigned int*)feat)[t] = (unsigned int)f2bf(a) | ((unsigned int)f2bf(c) << 16);
}

// ---- CSR build -------------------------------------------------------------
__global__ void k_hist(const int* __restrict__ dst, int* __restrict__ cnt) {
  int i = blockIdx.x * blockDim.x + threadIdx.x;
  if (i < N_EDGES) atomicAdd(&cnt[dst[i]], 1);
}

__global__ void k_scan(const int* __restrict__ cnt, int* __restrict__ off,
                       int* __restrict__ cursor) {
  __shared__ int wsum[16];
  __shared__ int carrySh;
  int tid = threadIdx.x, lane = tid & 63, wid = tid >> 6;
  if (tid == 0) carrySh = 0;
  __syncthreads();
  for (int base = 0; base < N_NODES; base += 1024) {
    int i = base + tid;
    int v = (i < N_NODES) ? cnt[i] : 0;
    int x = v;
#pragma unroll
    for (int d = 1; d < 64; d <<= 1) {
      int t = __shfl_up(x, d, 64);
      if (lane >= d) x += t;
    }
    if (lane == 63) wsum[wid] = x;
    __syncthreads();
    int carry = carrySh;
    if (wid == 0) {
      int s = (lane < 16) ? wsum[lane] : 0;
#pragma unroll
      for (int d = 1; d < 16; d <<= 1) {
        int t = __shfl_up(s, d, 64);
        if (lane >= d) s += t;
      }
      if (lane < 16) wsum[lane] = s;
    }
    __syncthreads();
    int woff = (wid > 0) ? wsum[wid - 1] : 0;
    int excl = carry + woff + x - v;
    if (i < N_NODES) { off[i] = excl; cursor[i] = excl; }
    int total = wsum[15];
    __syncthreads();
    if (tid == 0) carrySh = carry + total;
    __syncthreads();
  }
  if (threadIdx.x == 0) off[N_NODES] = carrySh;
}

__global__ void k_scatter(const int* __restrict__ src, const int* __restrict__ dst,
                          int* __restrict__ cursor, int* __restrict__ csr) {
  int i = blockIdx.x * blockDim.x + threadIdx.x;
  if (i < N_EDGES) {
    int pos = atomicAdd(&cursor[dst[i]], 1);
    csr[pos] = src[i];
  }
}

// ---- aggregation: wave per node, bf16 gather, fp32 accumulate --------------
__global__ void k_agg(const unsigned short* __restrict__ feat,
                      const float* __restrict__ geps_p,
                      const int* __restrict__ off, const int* __restrict__ csr,
                      unsigned short* __restrict__ agg) {
  int wave = (blockIdx.x * blockDim.x + threadIdx.x) >> 6;
  int lane = threadIdx.x & 63;
  if (wave >= N_NODES) return;
  int n = wave;
  float ge = 1.0f + geps_p[0];
  uint2 u = *((const uint2*)(feat + (long)n * F_PACK) + lane);  // k = lane*4 .. +3
  float a0 = ge * bflo(u.x), a1 = ge * bfhi(u.x);
  float a2 = ge * bflo(u.y), a3 = ge * bfhi(u.y);
  int e = off[n], e1 = off[n + 1];
  for (; e + 1 < e1; e += 2) {
    int s0 = csr[e], s1 = csr[e + 1];
    uint2 v0 = *((const uint2*)(feat + (long)s0 * F_PACK) + lane);
    uint2 v1 = *((const uint2*)(feat + (long)s1 * F_PACK) + lane);
    a0 += bflo(v0.x); a1 += bfhi(v0.x); a2 += bflo(v0.y); a3 += bfhi(v0.y);
    a0 += bflo(v1.x); a1 += bfhi(v1.x); a2 += bflo(v1.y); a3 += bfhi(v1.y);
  }
  if (e < e1) {
    uint2 v0 = *((const uint2*)(feat + (long)csr[e] * F_PACK) + lane);
    a0 += bflo(v0.x); a1 += bfhi(v0.x); a2 += bflo(v0.y); a3 += bfhi(v0.y);
  }
  uint2 o;
  o.x = (unsigned int)f2bf(a0) | ((unsigned int)f2bf(a1) << 16);
  o.y = (unsigned int)f2bf(a2) | ((unsigned int)f2bf(a3) << 16);
  *((uint2*)(agg + (long)n * F_PACK) + lane) = o;
}

// ---- MFMA GEMM + bias + ReLU + node-sum ------------------------------------
// A[m][k]: m=lane&15, k=quad*8+j (16B contiguous).  B[k][n]: n=lane&15.
// C/D: col=lane&15 (=out), row=quad*4+reg (=node).  Shared K=128 computed once,
// each sample = ONE extra MFMA seeded with C=shared accumulator.
__global__ __launch_bounds__(256) void k_gemm(const unsigned short* __restrict__ agg,
    const float* __restrict__ W, const float* __restrict__ b,
    float* __restrict__ partials) {
  int tid = threadIdx.x;
  int lane = tid & 63;
  int w = tid >> 6;          // wave -> n-tiles {2w, 2w+1}
  int col = lane & 15;
  int quad = lane >> 4;

  bf16x8 Bsh[2][4];
  bf16x8 Bep[2];
  float bias[2];
#pragma unroll
  for (int i = 0; i < 2; ++i) {
    int obase = (2 * w + i) * 16;
    bias[i] = b[obase + col];
#pragma unroll
    for (int kb = 0; kb < 4; ++kb) {
      bf16x8 f;
#pragma unroll
      for (int j = 0; j < 8; ++j) {
        int k = kb * 32 + quad * 8 + j;
        int wr = (k < 96) ? k : k + 32;            // h block lives at W rows 128..159
        f[j] = (short)f2bf(W[wr * D_OUTF + obase + col]);
      }
      Bsh[i][kb] = f;
    }
    bf16x8 g;
#pragma unroll
    for (int j = 0; j < 8; ++j)
      g[j] = (short)f2bf(W[(96 + quad * 8 + j) * D_OUTF + obase + col]);
    Bep[i] = g;
  }

  f32x4 psum[4][2];
#pragma unroll
  for (int s = 0; s < 4; ++s)
#pragma unroll
    for (int i = 0; i < 2; ++i) psum[s][i] = (f32x4){0.f, 0.f, 0.f, 0.f};

  for (int t = blockIdx.x; t < NTILES; t += gridDim.x) {
    const unsigned short* arow = agg + (long)(t * 16 + col) * F_PACK;
    bf16x8 Ash[4];
#pragma unroll
    for (int kb = 0; kb < 4; ++kb)
      Ash[kb] = *(const bf16x8*)(arow + kb * 32 + quad * 8);
    f32x4 csh[2];
    csh[0] = (f32x4){0.f, 0.f, 0.f, 0.f};
    csh[1] = (f32x4){0.f, 0.f, 0.f, 0.f};
#pragma unroll
    for (int kb = 0; kb < 4; ++kb) {
      csh[0] = __builtin_amdgcn_mfma_f32_16x16x32_bf16(Ash[kb], Bsh[0][kb], csh[0], 0, 0, 0);
      csh[1] = __builtin_amdgcn_mfma_f32_16x16x32_bf16(Ash[kb], Bsh[1][kb], csh[1], 0, 0, 0);
    }
#pragma unroll
    for (int s = 0; s < 4; ++s) {
      bf16x8 Aep = *(const bf16x8*)(arow + 128 + s * 32 + quad * 8);
#pragma unroll
      for (int i = 0; i < 2; ++i) {
        f32x4 c = __builtin_amdgcn_mfma_f32_16x16x32_bf16(Aep, Bep[i], csh[i], 0, 0, 0);
#pragma unroll
        for (int r = 0; r < 4; ++r)
          psum[s][i][r] += fmaxf(c[r] + bias[i], 0.f);
      }
    }
  }

#pragma unroll
  for (int s = 0; s < 4; ++s)
#pragma unroll
    for (int i = 0; i < 2; ++i) {
      float v = psum[s][i][0] + psum[s][i][1] + psum[s][i][2] + psum[s][i][3];
      v += __shfl_xor(v, 16, 64);
      v += __shfl_xor(v, 32, 64);
      if (quad == 0)
        partials[blockIdx.x * 512 + s * 128 + (2 * w + i) * 16 + col] = v;
    }
}

__global__ void k_reduce(const float* __restrict__ partials, float* __restrict__ means) {
  int idx = blockIdx.x * 64 + threadIdx.x;   // 8 blocks x 64 -> 512 outputs
  float t = 0.f;
  for (int blk = 0; blk < GEMM_BLOCKS; ++blk) t += partials[blk * 512 + idx];
  means[idx] = fmaxf(t * (1.0f / (float)N_NODES), 0.f);
}

// ---- broadcast output + epsilon passthrough --------------------------------
#define OUT0_F4 6400000L
#define EPS_F4  1600000L
__global__ void k_out(const float* __restrict__ means, const float* __restrict__ eps,
                      float* __restrict__ out) {
  long i = (long)blockIdx.x * blockDim.x + threadIdx.x;
  if (i < OUT0_F4) {
    int o4 = (int)(i & 31);
    long sn = i >> 5;
    int s = (int)(sn / N_NODES);
    ((float4*)out)[i] = ((const float4*)means)[s * 32 + o4];
  } else if (i < OUT0_F4 + EPS_F4) {
    long j = i - OUT0_F4;
    ((float4*)out)[OUT0_F4 + j] = ((const float4*)eps)[j];
  }
}

extern "C" void kernel_launch(void* const* d_in, const int* in_sizes, int n_in,
                              void* d_out, int out_size, void* d_ws, size_t ws_size,
                              hipStream_t stream) {
  const float* X    = (const float*)d_in[0];
  const float* h    = (const float*)d_in[1];
  const float* eps  = (const float*)d_in[2];
  const float* W    = (const float*)d_in[3];
  const float* b    = (const float*)d_in[4];
  const float* geps = (const float*)d_in[5];
  const int*   src  = (const int*)d_in[6];
  const int*   dst  = (const int*)d_in[7];
  float* out = (float*)d_out;

  char* w = (char*)d_ws;
  unsigned short* feat = (unsigned short*)w; w += (size_t)N_NODES * F_PACK * 2;  // 25.6 MB
  unsigned short* agg  = (unsigned short*)w; w += (size_t)N_NODES * F_PACK * 2;  // 25.6 MB
  int*   off      = (int*)w;   w += (size_t)(N_NODES + 16) * 4;
  int*   cnt      = (int*)w;   w += (size_t)N_NODES * 4;
  int*   cursor   = (int*)w;   w += (size_t)N_NODES * 4;
  int*   csr      = (int*)w;   w += (size_t)N_EDGES * 4;
  float* partials = (float*)w; w += (size_t)GEMM_BLOCKS * 512 * 4;
  float* means    = (float*)w; w += 512 * 4;

  hipMemsetAsync(cnt, 0, (size_t)N_NODES * 4, stream);

  int eb = (N_EDGES + 255) / 256;
  k_pack<<<(N_NODES * 128 + 255) / 256, 256, 0, stream>>>(X, h, eps, feat);
  k_hist<<<eb, 256, 0, stream>>>(dst, cnt);
  k_scan<<<1, 1024, 0, stream>>>(cnt, off, cursor);
  k_scatter<<<eb, 256, 0, stream>>>(src, dst, cursor, csr);

  k_agg<<<(N_NODES + 3) / 4, 256, 0, stream>>>(feat, geps, off, csr, agg);

  k_gemm<<<GEMM_BLOCKS, 256, 0, stream>>>(agg, W, b, partials);
  k_reduce<<<8, 64, 0, stream>>>(partials, means);

  long total_f4 = OUT0_F4 + EPS_F4;
  k_out<<<(int)((total_f4 + 255) / 256), 256, 0, stream>>>(means, eps, out);
}

// Round 3
// 397.849 us; speedup vs baseline: 2.0160x; 1.0627x over previous
//
#include <hip/hip_runtime.h>

#define N_NODES  50000
#define N_EDGES  800000
#define D_OUTF   128
#define F_PACK   256          // agg row: Xh(128) | eps counts (128)
#define NTILES   3125         // 50000 / 16, exact
#define GEMM_BLOCKS 512
#define NB1      196          // ceil(50000/256) scan blocks

typedef __attribute__((ext_vector_type(8))) short bf16x8;
typedef __attribute__((ext_vector_type(4))) float f32x4;

__device__ __forceinline__ unsigned short f2bf(float x) {
  unsigned int u = __float_as_uint(x);
  u += 0x7FFFu + ((u >> 16) & 1u);           // RNE
  return (unsigned short)(u >> 16);
}
__device__ __forceinline__ float bflo(unsigned int u) { return __uint_as_float(u << 16); }
__device__ __forceinline__ float bfhi(unsigned int u) { return __uint_as_float(u & 0xFFFF0000u); }
__device__ __forceinline__ unsigned int pack2(float a, float b) {
  return (unsigned int)f2bf(a) | ((unsigned int)f2bf(b) << 16);
}

// ---- pack X|h to bf16 [node][128] ------------------------------------------
__global__ void k_pack_xh(const float* __restrict__ X, const float* __restrict__ h,
                          unsigned int* __restrict__ featXH) {
  int t = blockIdx.x * blockDim.x + threadIdx.x;   // thread per (node, feature-pair)
  if (t >= N_NODES * 64) return;
  int node = t >> 6, f = (t & 63) << 1;            // f even, X/h boundary at 96 (even)
  float a, c;
  if (f < 96) { a = X[node * 96 + f];      c = X[node * 96 + f + 1]; }
  else        { a = h[node * 32 + f - 96]; c = h[node * 32 + f - 95]; }
  featXH[t] = pack2(a, c);
}

// ---- pack eps to bitmask: epsb[node] = uint4, word s, bit k ---------------
__global__ void k_pack_bits(const float* __restrict__ eps, unsigned int* __restrict__ epsb) {
  long g = (long)blockIdx.x * blockDim.x + threadIdx.x;   // over S*N*32 = 6.4M
  if (g >= (long)4 * N_NODES * 32) return;
  float v = eps[g];
  unsigned long long m = __ballot(v > 0.5f);
  int lane = threadIdx.x & 63;
  if ((lane & 31) == 0) {
    long idx = g >> 5;                       // = s*N + node
    int s = (int)(idx / N_NODES);
    int node = (int)(idx - (long)s * N_NODES);
    epsb[node * 4 + s] = (unsigned int)(m >> ((lane >> 5) * 32));
  }
}

// ---- CSR build -------------------------------------------------------------
__global__ void k_hist(const int* __restrict__ dst, int* __restrict__ cnt) {
  int i = blockIdx.x * blockDim.x + threadIdx.x;
  if (i < N_EDGES) atomicAdd(&cnt[dst[i]], 1);
}

// 3-pass parallel scan
__global__ void k_scan1(const int* __restrict__ cnt, int* __restrict__ excl,
                        int* __restrict__ bsum) {
  __shared__ int wpart[4];
  int tid = threadIdx.x, lane = tid & 63, wid = tid >> 6;
  int i = blockIdx.x * 256 + tid;
  int v = (i < N_NODES) ? cnt[i] : 0;
  int x = v;
#pragma unroll
  for (int d = 1; d < 64; d <<= 1) {
    int t = __shfl_up(x, d, 64);
    if (lane >= d) x += t;
  }
  if (lane == 63) wpart[wid] = x;
  __syncthreads();
  if (tid == 0) {
    int s = 0;
#pragma unroll
    for (int w = 0; w < 4; ++w) { int t = wpart[w]; wpart[w] = s; s += t; }
    bsum[blockIdx.x] = s;
  }
  __syncthreads();
  if (i < N_NODES) excl[i] = wpart[wid] + x - v;
}

__global__ void k_scan2(const int* __restrict__ bsum, int* __restrict__ boff) {
  __shared__ int sd[256];
  int tid = threadIdx.x;
  int v = (tid < NB1) ? bsum[tid] : 0;
  sd[tid] = v;
  __syncthreads();
  for (int d = 1; d < 256; d <<= 1) {
    int t = (tid >= d) ? sd[tid - d] : 0;
    __syncthreads();
    sd[tid] += t;
    __syncthreads();
  }
  if (tid < NB1) boff[tid] = sd[tid] - v;   // exclusive
}

__global__ void k_scan3(int* __restrict__ off, const int* __restrict__ boff,
                        int* __restrict__ cursor) {
  int i = blockIdx.x * 256 + threadIdx.x;
  if (i < N_NODES) {
    int o = off[i] + boff[blockIdx.x];
    off[i] = o;
    cursor[i] = o;
  }
  if (i == 0) off[N_NODES] = N_EDGES;
}

__global__ void k_scatter(const int* __restrict__ src, const int* __restrict__ dst,
                          int* __restrict__ cursor, int* __restrict__ csr) {
  int i = blockIdx.x * blockDim.x + threadIdx.x;
  if (i < N_EDGES) {
    int pos = atomicAdd(&cursor[dst[i]], 1);
    csr[pos] = src[i];
  }
}

// ---- aggregation: wave per node; X|h bf16 gather + eps bit-popcount --------
__device__ __forceinline__ unsigned int selw(uint4 b, int widx) {
  return widx == 0 ? b.x : widx == 1 ? b.y : widx == 2 ? b.z : b.w;
}

__global__ __launch_bounds__(256) void k_agg(const unsigned int* __restrict__ featXH,
                      const uint4* __restrict__ epsb,
                      const float* __restrict__ geps_p,
                      const int* __restrict__ off, const int* __restrict__ csr,
                      unsigned int* __restrict__ agg_u) {
  int wave = (blockIdx.x * blockDim.x + threadIdx.x) >> 6;
  int lane = threadIdx.x & 63;
  if (wave >= N_NODES) return;
  int n = wave;
  float ge = 1.0f + geps_p[0];
  int widx = lane >> 4, sh = (2 * lane) & 31;

  unsigned int su = featXH[n * 64 + lane];
  float a0 = ge * bflo(su), a1 = ge * bfhi(su);
  unsigned int sw = selw(epsb[n], widx);
  float e0 = ge * (float)((sw >> sh) & 1u);
  float e1 = ge * (float)((sw >> (sh + 1)) & 1u);
  int c0 = 0, c1 = 0;

  int e = off[n], eend = off[n + 1];
  for (; e + 1 < eend; e += 2) {
    int s0 = csr[e], s1 = csr[e + 1];
    unsigned int u0 = featXH[s0 * 64 + lane];
    unsigned int u1 = featXH[s1 * 64 + lane];
    uint4 b0 = epsb[s0];
    uint4 b1 = epsb[s1];
    a0 += bflo(u0); a1 += bfhi(u0);
    a0 += bflo(u1); a1 += bfhi(u1);
    unsigned int w0 = selw(b0, widx), w1 = selw(b1, widx);
    c0 += (int)((w0 >> sh) & 1u) + (int)((w1 >> sh) & 1u);
    c1 += (int)((w0 >> (sh + 1)) & 1u) + (int)((w1 >> (sh + 1)) & 1u);
  }
  if (e < eend) {
    int s0 = csr[e];
    unsigned int u0 = featXH[s0 * 64 + lane];
    uint4 b0 = epsb[s0];
    a0 += bflo(u0); a1 += bfhi(u0);
    unsigned int w0 = selw(b0, widx);
    c0 += (int)((w0 >> sh) & 1u);
    c1 += (int)((w0 >> (sh + 1)) & 1u);
  }
  e0 += (float)c0; e1 += (float)c1;

  unsigned int* ar = agg_u + n * 128;       // 256 bf16 = 128 uints per row
  ar[lane]      = pack2(a0, a1);            // packed features 2l, 2l+1 (Xh)
  ar[64 + lane] = pack2(e0, e1);            // packed features 128+2l, +2l+1 (eps)
}

// ---- MFMA GEMM + bias + ReLU + node-sum ------------------------------------
__global__ __launch_bounds__(256) void k_gemm(const unsigned short* __restrict__ agg,
    const float* __restrict__ W, const float* __restrict__ b,
    float* __restrict__ partials) {
  int tid = threadIdx.x;
  int lane = tid & 63;
  int w = tid >> 6;          // wave -> n-tiles {2w, 2w+1}
  int col = lane & 15;
  int quad = lane >> 4;

  bf16x8 Bsh[2][4];
  bf16x8 Bep[2];
  float bias[2];
#pragma unroll
  for (int i = 0; i < 2; ++i) {
    int obase = (2 * w + i) * 16;
    bias[i] = b[obase + col];
#pragma unroll
    for (int kb = 0; kb < 4; ++kb) {
      bf16x8 f;
#pragma unroll
      for (int j = 0; j < 8; ++j) {
        int k = kb * 32 + quad * 8 + j;
        int wr = (k < 96) ? k : k + 32;            // h block at W rows 128..159
        f[j] = (short)f2bf(W[wr * D_OUTF + obase + col]);
      }
      Bsh[i][kb] = f;
    }
    bf16x8 g;
#pragma unroll
    for (int j = 0; j < 8; ++j)
      g[j] = (short)f2bf(W[(96 + quad * 8 + j) * D_OUTF + obase + col]);
    Bep[i] = g;
  }

  f32x4 psum[4][2];
#pragma unroll
  for (int s = 0; s < 4; ++s)
#pragma unroll
    for (int i = 0; i < 2; ++i) psum[s][i] = (f32x4){0.f, 0.f, 0.f, 0.f};

  for (int t = blockIdx.x; t < NTILES; t += gridDim.x) {
    const unsigned short* arow = agg + (long)(t * 16 + col) * F_PACK;
    bf16x8 Ash[4];
#pragma unroll
    for (int kb = 0; kb < 4; ++kb)
      Ash[kb] = *(const bf16x8*)(arow + kb * 32 + quad * 8);
    f32x4 csh[2];
    csh[0] = (f32x4){0.f, 0.f, 0.f, 0.f};
    csh[1] = (f32x4){0.f, 0.f, 0.f, 0.f};
#pragma unroll
    for (int kb = 0; kb < 4; ++kb) {
      csh[0] = __builtin_amdgcn_mfma_f32_16x16x32_bf16(Ash[kb], Bsh[0][kb], csh[0], 0, 0, 0);
      csh[1] = __builtin_amdgcn_mfma_f32_16x16x32_bf16(Ash[kb], Bsh[1][kb], csh[1], 0, 0, 0);
    }
#pragma unroll
    for (int s = 0; s < 4; ++s) {
      bf16x8 Aep = *(const bf16x8*)(arow + 128 + s * 32 + quad * 8);
#pragma unroll
      for (int i = 0; i < 2; ++i) {
        f32x4 c = __builtin_amdgcn_mfma_f32_16x16x32_bf16(Aep, Bep[i], csh[i], 0, 0, 0);
#pragma unroll
        for (int r = 0; r < 4; ++r)
          psum[s][i][r] += fmaxf(c[r] + bias[i], 0.f);
      }
    }
  }

#pragma unroll
  for (int s = 0; s < 4; ++s)
#pragma unroll
    for (int i = 0; i < 2; ++i) {
      float v = psum[s][i][0] + psum[s][i][1] + psum[s][i][2] + psum[s][i][3];
      v += __shfl_xor(v, 16, 64);
      v += __shfl_xor(v, 32, 64);
      if (quad == 0)
        partials[blockIdx.x * 512 + s * 128 + (2 * w + i) * 16 + col] = v;
    }
}

__global__ void k_reduce(const float* __restrict__ partials, float* __restrict__ means) {
  int idx = blockIdx.x * 64 + threadIdx.x;   // 8 x 64 -> 512
  float t = 0.f;
  for (int blk = 0; blk < GEMM_BLOCKS; ++blk) t += partials[blk * 512 + idx];
  means[idx] = fmaxf(t * (1.0f / (float)N_NODES), 0.f);
}

// ---- broadcast output + epsilon passthrough --------------------------------
#define OUT0_F4 6400000L
#define EPS_F4  1600000L
__global__ void k_out(const float* __restrict__ means, const float* __restrict__ eps,
                      float* __restrict__ out) {
  long i = (long)blockIdx.x * blockDim.x + threadIdx.x;
  if (i < OUT0_F4) {
    int o4 = (int)(i & 31);
    long sn = i >> 5;
    int s = (int)(sn / N_NODES);
    ((float4*)out)[i] = ((const float4*)means)[s * 32 + o4];
  } else if (i < OUT0_F4 + EPS_F4) {
    long j = i - OUT0_F4;
    ((float4*)out)[OUT0_F4 + j] = ((const float4*)eps)[j];
  }
}

extern "C" void kernel_launch(void* const* d_in, const int* in_sizes, int n_in,
                              void* d_out, int out_size, void* d_ws, size_t ws_size,
                              hipStream_t stream) {
  const float* X    = (const float*)d_in[0];
  const float* h    = (const float*)d_in[1];
  const float* eps  = (const float*)d_in[2];
  const float* W    = (const float*)d_in[3];
  const float* b    = (const float*)d_in[4];
  const float* geps = (const float*)d_in[5];
  const int*   src  = (const int*)d_in[6];
  const int*   dst  = (const int*)d_in[7];
  float* out = (float*)d_out;

  char* w = (char*)d_ws;
  unsigned int*  featXH = (unsigned int*)w;  w += (size_t)N_NODES * 64 * 4;   // 12.8 MB
  unsigned int*  epsb   = (unsigned int*)w;  w += (size_t)N_NODES * 4 * 4;    // 0.8 MB (16B/node)
  unsigned int*  agg_u  = (unsigned int*)w;  w += (size_t)N_NODES * 128 * 4;  // 25.6 MB
  int*   off      = (int*)w;   w += (size_t)(N_NODES + 16) * 4;
  int*   cnt      = (int*)w;   w += (size_t)N_NODES * 4;
  int*   cursor   = (int*)w;   w += (size_t)N_NODES * 4;
  int*   csr      = (int*)w;   w += (size_t)N_EDGES * 4;
  int*   bsum     = (int*)w;   w += 256 * 4;
  int*   boff     = (int*)w;   w += 256 * 4;
  float* partials = (float*)w; w += (size_t)GEMM_BLOCKS * 512 * 4;
  float* means    = (float*)w; w += 512 * 4;

  hipMemsetAsync(cnt, 0, (size_t)N_NODES * 4, stream);

  int eb = (N_EDGES + 255) / 256;
  k_pack_xh<<<(N_NODES * 64 + 255) / 256, 256, 0, stream>>>(X, h, featXH);
  k_pack_bits<<<(4 * N_NODES * 32 + 255) / 256, 256, 0, stream>>>(eps, epsb);
  k_hist<<<eb, 256, 0, stream>>>(dst, cnt);
  k_scan1<<<NB1, 256, 0, stream>>>(cnt, off, bsum);
  k_scan2<<<1, 256, 0, stream>>>(bsum, boff);
  k_scan3<<<NB1, 256, 0, stream>>>(off, boff, cursor);
  k_scatter<<<eb, 256, 0, stream>>>(src, dst, cursor, csr);

  k_agg<<<(N_NODES + 3) / 4, 256, 0, stream>>>(featXH, (const uint4*)epsb, geps, off, csr, agg_u);

  k_gemm<<<GEMM_BLOCKS, 256, 0, stream>>>((const unsigned short*)agg_u, W, b, partials);
  k_reduce<<<8, 64, 0, stream>>>(partials, means);

  long total_f4 = OUT0_F4 + EPS_F4;
  k_out<<<(int)((total_f4 + 255) / 256), 256, 0, stream>>>(means, eps, out);
}

// Round 6
// 377.937 us; speedup vs baseline: 2.1222x; 1.0527x over previous
//
#include <hip/hip_runtime.h>

#define N_NODES  50000
#define N_EDGES  800000
#define D_OUTF   128
#define F_PACK   256          // agg row: Xh(128) | eps counts (128)
#define NTILES   3125         // 50000 / 16, exact
#define GEMM_BLOCKS 512
#define NB1      196          // ceil(50000/256) scan blocks

typedef __attribute__((ext_vector_type(8))) short bf16x8;
typedef __attribute__((ext_vector_type(4))) float f32x4;

__device__ __forceinline__ unsigned short f2bf(float x) {
  unsigned int u = __float_as_uint(x);
  u += 0x7FFFu + ((u >> 16) & 1u);           // RNE
  return (unsigned short)(u >> 16);
}
__device__ __forceinline__ float bflo(unsigned int u) { return __uint_as_float(u << 16); }
__device__ __forceinline__ float bfhi(unsigned int u) { return __uint_as_float(u & 0xFFFF0000u); }
__device__ __forceinline__ unsigned int pack2(float a, float b) {
  return (unsigned int)f2bf(a) | ((unsigned int)f2bf(b) << 16);
}
__device__ __forceinline__ unsigned int selw(uint4 b, int widx) {
  return widx == 0 ? b.x : widx == 1 ? b.y : widx == 2 ? b.z : b.w;
}

// ---- pack X|h to bf16 [node][128] ------------------------------------------
__global__ void k_pack_xh(const float* __restrict__ X, const float* __restrict__ h,
                          unsigned int* __restrict__ featXH) {
  int t = blockIdx.x * blockDim.x + threadIdx.x;   // thread per (node, feature-pair)
  if (t >= N_NODES * 64) return;
  int node = t >> 6, f = (t & 63) << 1;            // f even, X/h boundary at 96 (even)
  float a, c;
  if (f < 96) { a = X[node * 96 + f];      c = X[node * 96 + f + 1]; }
  else        { a = h[node * 32 + f - 96]; c = h[node * 32 + f - 95]; }
  featXH[t] = pack2(a, c);
}

// ---- pack eps to bitmask: epsb[node] = uint4, word s, bit k ---------------
__global__ void k_pack_bits(const float* __restrict__ eps, unsigned int* __restrict__ epsb) {
  long g = (long)blockIdx.x * blockDim.x + threadIdx.x;   // over S*N*32 = 6.4M
  if (g >= (long)4 * N_NODES * 32) return;
  float v = eps[g];
  unsigned long long m = __ballot(v > 0.5f);
  int lane = threadIdx.x & 63;
  if ((lane & 31) == 0) {
    long idx = g >> 5;                       // = s*N + node
    int s = (int)(idx / N_NODES);
    int node = (int)(idx - (long)s * N_NODES);
    epsb[node * 4 + s] = (unsigned int)(m >> ((lane >> 5) * 32));
  }
}

// ---- CSR build -------------------------------------------------------------
__global__ void k_hist(const int* __restrict__ dst, int* __restrict__ cnt) {
  int i = blockIdx.x * blockDim.x + threadIdx.x;
  if (i < N_EDGES) atomicAdd(&cnt[dst[i]], 1);
}

__global__ void k_scan1(const int* __restrict__ cnt, int* __restrict__ excl,
                        int* __restrict__ bsum) {
  __shared__ int wpart[4];
  int tid = threadIdx.x, lane = tid & 63, wid = tid >> 6;
  int i = blockIdx.x * 256 + tid;
  int v = (i < N_NODES) ? cnt[i] : 0;
  int x = v;
#pragma unroll
  for (int d = 1; d < 64; d <<= 1) {
    int t = __shfl_up(x, d, 64);
    if (lane >= d) x += t;
  }
  if (lane == 63) wpart[wid] = x;
  __syncthreads();
  if (tid == 0) {
    int s = 0;
#pragma unroll
    for (int w = 0; w < 4; ++w) { int t = wpart[w]; wpart[w] = s; s += t; }
    bsum[blockIdx.x] = s;
  }
  __syncthreads();
  if (i < N_NODES) excl[i] = wpart[wid] + x - v;
}

__global__ void k_scan2(const int* __restrict__ bsum, int* __restrict__ boff) {
  __shared__ int sd[256];
  int tid = threadIdx.x;
  int v = (tid < NB1) ? bsum[tid] : 0;
  sd[tid] = v;
  __syncthreads();
  for (int d = 1; d < 256; d <<= 1) {
    int t = (tid >= d) ? sd[tid - d] : 0;
    __syncthreads();
    sd[tid] += t;
    __syncthreads();
  }
  if (tid < NB1) boff[tid] = sd[tid] - v;
}

__global__ void k_scan3(int* __restrict__ off, const int* __restrict__ boff,
                        int* __restrict__ cursor) {
  int i = blockIdx.x * 256 + threadIdx.x;
  if (i < N_NODES) {
    int o = off[i] + boff[blockIdx.x];
    off[i] = o;
    cursor[i] = o;
  }
  if (i == 0) off[N_NODES] = N_EDGES;
}

__global__ void k_scatter(const int* __restrict__ src, const int* __restrict__ dst,
                          int* __restrict__ cursor, int* __restrict__ csr) {
  int i = blockIdx.x * blockDim.x + threadIdx.x;
  if (i < N_EDGES) {
    int pos = atomicAdd(&cursor[dst[i]], 1);
    csr[pos] = src[i];
  }
}

// ---- aggregation: 16-lane group per node, dwordx4 gather -------------------
// Lane li covers XH features 8li..8li+7 (one uint4/edge) and eps features
// 128+8li..+7 = byte (li&3) of epsb word (li>>2). agg layout identical to R3.
__global__ __launch_bounds__(256) void k_agg16(
    const uint4* __restrict__ feat4, const uint4* __restrict__ epsb,
    const float* __restrict__ geps_p, const int* __restrict__ off,
    const int* __restrict__ csr, uint4* __restrict__ agg4) {
  int gt = blockIdx.x * blockDim.x + threadIdx.x;
  int n  = gt >> 4;                 // group id = node (grid exact: 3125*256/16)
  int li = gt & 15;
  if (n >= N_NODES) return;
  float ge = 1.0f + geps_p[0];
  int wsel = li >> 2, bsh = (li & 3) * 8;

  uint4 sf = feat4[n * 16 + li];
  float af0 = ge * bflo(sf.x), af1 = ge * bfhi(sf.x);
  float af2 = ge * bflo(sf.y), af3 = ge * bfhi(sf.y);
  float af4 = ge * bflo(sf.z), af5 = ge * bfhi(sf.z);
  float af6 = ge * bflo(sf.w), af7 = ge * bfhi(sf.w);
  unsigned int Bself = (selw(epsb[n], wsel) >> bsh) & 0xFFu;
  int c0 = 0, c1 = 0, c2 = 0, c3 = 0, c4 = 0, c5 = 0, c6 = 0, c7 = 0;

  int e = off[n], e1 = off[n + 1];
  for (; e < e1; ++e) {
    int s0 = csr[e];
    uint4 f0 = feat4[s0 * 16 + li];
    unsigned int B0 = (selw(epsb[s0], wsel) >> bsh) & 0xFFu;
    af0 += bflo(f0.x); af1 += bfhi(f0.x);
    af2 += bflo(f0.y); af3 += bfhi(f0.y);
    af4 += bflo(f0.z); af5 += bfhi(f0.z);
    af6 += bflo(f0.w); af7 += bfhi(f0.w);
    c0 += (int)(B0 & 1u);        c1 += (int)((B0 >> 1) & 1u);
    c2 += (int)((B0 >> 2) & 1u); c3 += (int)((B0 >> 3) & 1u);
    c4 += (int)((B0 >> 4) & 1u); c5 += (int)((B0 >> 5) & 1u);
    c6 += (int)((B0 >> 6) & 1u); c7 += (int)((B0 >> 7) & 1u);
  }

  float ev0 = ge * (float)(Bself & 1u)        + (float)c0;
  float ev1 = ge * (float)((Bself >> 1) & 1u) + (float)c1;
  float ev2 = ge * (float)((Bself >> 2) & 1u) + (float)c2;
  float ev3 = ge * (float)((Bself >> 3) & 1u) + (float)c3;
  float ev4 = ge * (float)((Bself >> 4) & 1u) + (float)c4;
  float ev5 = ge * (float)((Bself >> 5) & 1u) + (float)c5;
  float ev6 = ge * (float)((Bself >> 6) & 1u) + (float)c6;
  float ev7 = ge * (float)((Bself >> 7) & 1u) + (float)c7;

  uint4 oXh, oEp;
  oXh.x = pack2(af0, af1); oXh.y = pack2(af2, af3);
  oXh.z = pack2(af4, af5); oXh.w = pack2(af6, af7);
  oEp.x = pack2(ev0, ev1); oEp.y = pack2(ev2, ev3);
  oEp.z = pack2(ev4, ev5); oEp.w = pack2(ev6, ev7);
  agg4[n * 32 + li]      = oXh;    // uints n*128 + 4li..+3 : features 8li..8li+7
  agg4[n * 32 + 16 + li] = oEp;    // uints n*128 + 64+4li  : features 128+8li..+7
}

// ---- MFMA GEMM + bias + ReLU + node-sum (VERBATIM R3, verified) ------------
__global__ __launch_bounds__(256) void k_gemm(const unsigned short* __restrict__ agg,
    const float* __restrict__ W, const float* __restrict__ b,
    float* __restrict__ partials) {
  int tid = threadIdx.x;
  int lane = tid & 63;
  int w = tid >> 6;          // wave -> n-tiles {2w, 2w+1}
  int col = lane & 15;
  int quad = lane >> 4;

  bf16x8 Bsh[2][4];
  bf16x8 Bep[2];
  float bias[2];
#pragma unroll
  for (int i = 0; i < 2; ++i) {
    int obase = (2 * w + i) * 16;
    bias[i] = b[obase + col];
#pragma unroll
    for (int kb = 0; kb < 4; ++kb) {
      bf16x8 f;
#pragma unroll
      for (int j = 0; j < 8; ++j) {
        int k = kb * 32 + quad * 8 + j;
        int wr = (k < 96) ? k : k + 32;            // h block at W rows 128..159
        f[j] = (short)f2bf(W[wr * D_OUTF + obase + col]);
      }
      Bsh[i][kb] = f;
    }
    bf16x8 g;
#pragma unroll
    for (int j = 0; j < 8; ++j)
      g[j] = (short)f2bf(W[(96 + quad * 8 + j) * D_OUTF + obase + col]);
    Bep[i] = g;
  }

  f32x4 psum[4][2];
#pragma unroll
  for (int s = 0; s < 4; ++s)
#pragma unroll
    for (int i = 0; i < 2; ++i) psum[s][i] = (f32x4){0.f, 0.f, 0.f, 0.f};

  for (int t = blockIdx.x; t < NTILES; t += gridDim.x) {
    const unsigned short* arow = agg + (long)(t * 16 + col) * F_PACK;
    bf16x8 Ash[4];
#pragma unroll
    for (int kb = 0; kb < 4; ++kb)
      Ash[kb] = *(const bf16x8*)(arow + kb * 32 + quad * 8);
    f32x4 csh[2];
    csh[0] = (f32x4){0.f, 0.f, 0.f, 0.f};
    csh[1] = (f32x4){0.f, 0.f, 0.f, 0.f};
#pragma unroll
    for (int kb = 0; kb < 4; ++kb) {
      csh[0] = __builtin_amdgcn_mfma_f32_16x16x32_bf16(Ash[kb], Bsh[0][kb], csh[0], 0, 0, 0);
      csh[1] = __builtin_amdgcn_mfma_f32_16x16x32_bf16(Ash[kb], Bsh[1][kb], csh[1], 0, 0, 0);
    }
#pragma unroll
    for (int s = 0; s < 4; ++s) {
      bf16x8 Aep = *(const bf16x8*)(arow + 128 + s * 32 + quad * 8);
#pragma unroll
      for (int i = 0; i < 2; ++i) {
        f32x4 c = __builtin_amdgcn_mfma_f32_16x16x32_bf16(Aep, Bep[i], csh[i], 0, 0, 0);
#pragma unroll
        for (int r = 0; r < 4; ++r)
          psum[s][i][r] += fmaxf(c[r] + bias[i], 0.f);
      }
    }
  }

#pragma unroll
  for (int s = 0; s < 4; ++s)
#pragma unroll
    for (int i = 0; i < 2; ++i) {
      float v = psum[s][i][0] + psum[s][i][1] + psum[s][i][2] + psum[s][i][3];
      v += __shfl_xor(v, 16, 64);
      v += __shfl_xor(v, 32, 64);
      if (quad == 0)
        partials[blockIdx.x * 512 + s * 128 + (2 * w + i) * 16 + col] = v;
    }
}

__global__ void k_reduce(const float* __restrict__ partials, float* __restrict__ means) {
  int idx = blockIdx.x * 64 + threadIdx.x;   // 8 x 64 -> 512
  float t = 0.f;
  for (int blk = 0; blk < GEMM_BLOCKS; ++blk) t += partials[blk * 512 + idx];
  means[idx] = fmaxf(t * (1.0f / (float)N_NODES), 0.f);
}

// ---- broadcast output + epsilon passthrough --------------------------------
#define OUT0_F4 6400000L
#define EPS_F4  1600000L
__global__ void k_out(const float* __restrict__ means, const float* __restrict__ eps,
                      float* __restrict__ out) {
  long i = (long)blockIdx.x * blockDim.x + threadIdx.x;
  if (i < OUT0_F4) {
    int o4 = (int)(i & 31);
    long sn = i >> 5;
    int s = (int)(sn / N_NODES);
    ((float4*)out)[i] = ((const float4*)means)[s * 32 + o4];
  } else if (i < OUT0_F4 + EPS_F4) {
    long j = i - OUT0_F4;
    ((float4*)out)[OUT0_F4 + j] = ((const float4*)eps)[j];
  }
}

extern "C" void kernel_launch(void* const* d_in, const int* in_sizes, int n_in,
                              void* d_out, int out_size, void* d_ws, size_t ws_size,
                              hipStream_t stream) {
  const float* X    = (const float*)d_in[0];
  const float* h    = (const float*)d_in[1];
  const float* eps  = (const float*)d_in[2];
  const float* W    = (const float*)d_in[3];
  const float* b    = (const float*)d_in[4];
  const float* geps = (const float*)d_in[5];
  const int*   src  = (const int*)d_in[6];
  const int*   dst  = (const int*)d_in[7];
  float* out = (float*)d_out;

  char* w = (char*)d_ws;
  unsigned int*  featXH = (unsigned int*)w;  w += (size_t)N_NODES * 64 * 4;   // 12.8 MB
  unsigned int*  epsb   = (unsigned int*)w;  w += (size_t)N_NODES * 4 * 4;    // 0.8 MB
  unsigned int*  agg_u  = (unsigned int*)w;  w += (size_t)N_NODES * 128 * 4;  // 25.6 MB
  int*   off      = (int*)w;   w += (size_t)(N_NODES + 16) * 4;
  int*   cnt      = (int*)w;   w += (size_t)N_NODES * 4;
  int*   cursor   = (int*)w;   w += (size_t)N_NODES * 4;
  int*   csr      = (int*)w;   w += (size_t)N_EDGES * 4;
  int*   bsum     = (int*)w;   w += 256 * 4;
  int*   boff     = (int*)w;   w += 256 * 4;
  float* partials = (float*)w; w += (size_t)GEMM_BLOCKS * 512 * 4;
  float* means    = (float*)w; w += 512 * 4;

  hipMemsetAsync(cnt, 0, (size_t)N_NODES * 4, stream);

  int eb = (N_EDGES + 255) / 256;
  k_pack_xh<<<(N_NODES * 64 + 255) / 256, 256, 0, stream>>>(X, h, featXH);
  k_pack_bits<<<(4 * N_NODES * 32 + 255) / 256, 256, 0, stream>>>(eps, epsb);
  k_hist<<<eb, 256, 0, stream>>>(dst, cnt);
  k_scan1<<<NB1, 256, 0, stream>>>(cnt, off, bsum);
  k_scan2<<<1, 256, 0, stream>>>(bsum, boff);
  k_scan3<<<NB1, 256, 0, stream>>>(off, boff, cursor);
  k_scatter<<<eb, 256, 0, stream>>>(src, dst, cursor, csr);

  k_agg16<<<NTILES, 256, 0, stream>>>((const uint4*)featXH, (const uint4*)epsb,
                                      geps, off, csr, (uint4*)agg_u);

  k_gemm<<<GEMM_BLOCKS, 256, 0, stream>>>((const unsigned short*)agg_u, W, b, partials);
  k_reduce<<<8, 64, 0, stream>>>(partials, means);

  long total_f4 = OUT0_F4 + EPS_F4;
  k_out<<<(int)((total_f4 + 255) / 256), 256, 0, stream>>>(means, eps, out);
}

// Round 7
// 355.086 us; speedup vs baseline: 2.2588x; 1.0644x over previous
//
#include <hip/hip_runtime.h>

#define N_NODES  50000
#define N_EDGES  800000
#define D_OUTF   128
#define F_PACK   256          // agg row: Xh(128) | eps counts (128)
#define NTILES   3125         // 50000 / 16, exact
#define GEMM_BLOCKS 512
#define NB1      196          // ceil(50000/256) scan blocks
// merged pack kernel block ranges
#define PBX 12500             // pack_xh: 50000*64 threads (exact)
#define PBB 25000             // pack_bits: 6.4M threads (exact)
#define PBZ 196               // zero cnt
#define PB_TOT (PBX + PBB + PBZ)

typedef __attribute__((ext_vector_type(8))) short bf16x8;
typedef __attribute__((ext_vector_type(4))) float f32x4;

__device__ __forceinline__ unsigned short f2bf(float x) {
  unsigned int u = __float_as_uint(x);
  u += 0x7FFFu + ((u >> 16) & 1u);           // RNE
  return (unsigned short)(u >> 16);
}
__device__ __forceinline__ float bflo(unsigned int u) { return __uint_as_float(u << 16); }
__device__ __forceinline__ float bfhi(unsigned int u) { return __uint_as_float(u & 0xFFFF0000u); }
__device__ __forceinline__ unsigned int pack2(float a, float b) {
  return (unsigned int)f2bf(a) | ((unsigned int)f2bf(b) << 16);
}
// byte-spread popcount helpers: rep = byte B replicated 4x.
// spreadLo -> bytes {bit0,bit1,bit2,bit3}; spreadHi -> bytes {bit4,bit5,bit6,bit7}
__device__ __forceinline__ unsigned int spreadLo(unsigned int rep) {
  return (((rep & 0x08040201u) + 0x7F7F7F7Fu) >> 7) & 0x01010101u;
}
__device__ __forceinline__ unsigned int spreadHi(unsigned int rep) {
  return (((rep & 0x80402010u) + 0x7F7F7F7Fu) >> 7) & 0x01010101u;
}

// ---- merged prep: pack X|h -> bf16, eps -> bitmask, zero cnt ---------------
__global__ void k_pack(const float* __restrict__ X, const float* __restrict__ h,
                       const float* __restrict__ eps,
                       unsigned int* __restrict__ featXH,
                       unsigned int* __restrict__ epsb, int* __restrict__ cnt) {
  int blk = blockIdx.x, tid = threadIdx.x;
  if (blk < PBX) {
    int t = blk * 256 + tid;                 // < 3.2M exact, no guard
    int node = t >> 6, f = (t & 63) << 1;    // X/h boundary at 96 (even)
    float a, c;
    if (f < 96) { a = X[node * 96 + f];      c = X[node * 96 + f + 1]; }
    else        { a = h[node * 32 + f - 96]; c = h[node * 32 + f - 95]; }
    featXH[t] = pack2(a, c);
  } else if (blk < PBX + PBB) {
    long g = (long)(blk - PBX) * 256 + tid;  // < 6.4M exact
    float v = eps[g];
    unsigned long long m = __ballot(v > 0.5f);
    int lane = tid & 63;
    if ((lane & 31) == 0) {
      long idx = g >> 5;                     // = s*N + node
      int s = (int)(idx / N_NODES);
      int node = (int)(idx - (long)s * N_NODES);
      epsb[node * 4 + s] = (unsigned int)(m >> ((lane >> 5) * 32));
    }
  } else {
    int i = (blk - PBX - PBB) * 256 + tid;
    if (i < N_NODES) cnt[i] = 0;
  }
}

// ---- CSR build -------------------------------------------------------------
__global__ void k_hist(const int* __restrict__ dst, int* __restrict__ cnt) {
  int i = blockIdx.x * blockDim.x + threadIdx.x;
  if (i < N_EDGES) atomicAdd(&cnt[dst[i]], 1);
}

__global__ void k_scan1(const int* __restrict__ cnt, int* __restrict__ excl,
                        int* __restrict__ bsum) {
  __shared__ int wpart[4];
  int tid = threadIdx.x, lane = tid & 63, wid = tid >> 6;
  int i = blockIdx.x * 256 + tid;
  int v = (i < N_NODES) ? cnt[i] : 0;
  int x = v;
#pragma unroll
  for (int d = 1; d < 64; d <<= 1) {
    int t = __shfl_up(x, d, 64);
    if (lane >= d) x += t;
  }
  if (lane == 63) wpart[wid] = x;
  __syncthreads();
  if (tid == 0) {
    int s = 0;
#pragma unroll
    for (int w = 0; w < 4; ++w) { int t = wpart[w]; wpart[w] = s; s += t; }
    bsum[blockIdx.x] = s;
  }
  __syncthreads();
  if (i < N_NODES) excl[i] = wpart[wid] + x - v;
}

__global__ void k_scan2(const int* __restrict__ bsum, int* __restrict__ boff) {
  __shared__ int sd[256];
  int tid = threadIdx.x;
  int v = (tid < NB1) ? bsum[tid] : 0;
  sd[tid] = v;
  __syncthreads();
  for (int d = 1; d < 256; d <<= 1) {
    int t = (tid >= d) ? sd[tid - d] : 0;
    __syncthreads();
    sd[tid] += t;
    __syncthreads();
  }
  if (tid < NB1) boff[tid] = sd[tid] - v;
}

__global__ void k_scan3(int* __restrict__ off, const int* __restrict__ boff,
                        int* __restrict__ cursor) {
  int i = blockIdx.x * 256 + threadIdx.x;
  if (i < N_NODES) {
    int o = off[i] + boff[blockIdx.x];
    off[i] = o;
    cursor[i] = o;
  }
  if (i == 0) off[N_NODES] = N_EDGES;
}

__global__ void k_scatter(const int* __restrict__ src, const int* __restrict__ dst,
                          int* __restrict__ cursor, int* __restrict__ csr) {
  int i = blockIdx.x * blockDim.x + threadIdx.x;
  if (i < N_EDGES) {
    int pos = atomicAdd(&cursor[dst[i]], 1);
    csr[pos] = src[i];
  }
}

// ---- aggregation: 16-lane group per node, dwordx4 gather, 2-edge unroll ----
// Lane li covers XH features 8li..8li+7 (one uint4/edge) and eps features
// 128+8li..+7 = byte (li&3) of epsb word (li>>2). agg layout identical to R3/R6.
__global__ __launch_bounds__(256) void k_agg16(
    const uint4* __restrict__ feat4, const unsigned int* __restrict__ epsw,
    const float* __restrict__ geps_p, const int* __restrict__ off,
    const int* __restrict__ csr, uint4* __restrict__ agg4) {
  int gt = blockIdx.x * blockDim.x + threadIdx.x;
  int n  = gt >> 4;                 // group id = node (grid exact: 3125*256/16)
  int li = gt & 15;
  if (n >= N_NODES) return;
  float ge = 1.0f + geps_p[0];
  int wsel = li >> 2, bsh = (li & 3) * 8;

  uint4 sf = feat4[n * 16 + li];
  float af0 = ge * bflo(sf.x), af1 = ge * bfhi(sf.x);
  float af2 = ge * bflo(sf.y), af3 = ge * bfhi(sf.y);
  float af4 = ge * bflo(sf.z), af5 = ge * bfhi(sf.z);
  float af6 = ge * bflo(sf.w), af7 = ge * bfhi(sf.w);
  unsigned int Bself = (epsw[n * 4 + wsel] >> bsh) & 0xFFu;
  unsigned int accLo = 0, accHi = 0;

  int e = off[n], e1 = off[n + 1];
  for (; e + 1 < e1; e += 2) {
    int s0 = csr[e], s1 = csr[e + 1];
    uint4 f0 = feat4[s0 * 16 + li];
    uint4 f1 = feat4[s1 * 16 + li];
    unsigned int w0 = epsw[s0 * 4 + wsel];
    unsigned int w1 = epsw[s1 * 4 + wsel];
    af0 += bflo(f0.x) + bflo(f1.x);  af1 += bfhi(f0.x) + bfhi(f1.x);
    af2 += bflo(f0.y) + bflo(f1.y);  af3 += bfhi(f0.y) + bfhi(f1.y);
    af4 += bflo(f0.z) + bflo(f1.z);  af5 += bfhi(f0.z) + bfhi(f1.z);
    af6 += bflo(f0.w) + bflo(f1.w);  af7 += bfhi(f0.w) + bfhi(f1.w);
    unsigned int B0 = (w0 >> bsh) & 0xFFu;
    unsigned int B1 = (w1 >> bsh) & 0xFFu;
    unsigned int r0 = B0 | (B0 << 8);  r0 |= r0 << 16;
    unsigned int r1 = B1 | (B1 << 8);  r1 |= r1 << 16;
    accLo += spreadLo(r0) + spreadLo(r1);
    accHi += spreadHi(r0) + spreadHi(r1);
  }
  if (e < e1) {
    int s0 = csr[e];
    uint4 f0 = feat4[s0 * 16 + li];
    unsigned int w0 = epsw[s0 * 4 + wsel];
    af0 += bflo(f0.x); af1 += bfhi(f0.x);
    af2 += bflo(f0.y); af3 += bfhi(f0.y);
    af4 += bflo(f0.z); af5 += bfhi(f0.z);
    af6 += bflo(f0.w); af7 += bfhi(f0.w);
    unsigned int B0 = (w0 >> bsh) & 0xFFu;
    unsigned int r0 = B0 | (B0 << 8);  r0 |= r0 << 16;
    accLo += spreadLo(r0);
    accHi += spreadHi(r0);
  }

  float ev0 = ge * (float)(Bself & 1u)        + (float)(accLo & 0xFFu);
  float ev1 = ge * (float)((Bself >> 1) & 1u) + (float)((accLo >> 8) & 0xFFu);
  float ev2 = ge * (float)((Bself >> 2) & 1u) + (float)((accLo >> 16) & 0xFFu);
  float ev3 = ge * (float)((Bself >> 3) & 1u) + (float)((accLo >> 24) & 0xFFu);
  float ev4 = ge * (float)((Bself >> 4) & 1u) + (float)(accHi & 0xFFu);
  float ev5 = ge * (float)((Bself >> 5) & 1u) + (float)((accHi >> 8) & 0xFFu);
  float ev6 = ge * (float)((Bself >> 6) & 1u) + (float)((accHi >> 16) & 0xFFu);
  float ev7 = ge * (float)((Bself >> 7) & 1u) + (float)((accHi >> 24) & 0xFFu);

  uint4 oXh, oEp;
  oXh.x = pack2(af0, af1); oXh.y = pack2(af2, af3);
  oXh.z = pack2(af4, af5); oXh.w = pack2(af6, af7);
  oEp.x = pack2(ev0, ev1); oEp.y = pack2(ev2, ev3);
  oEp.z = pack2(ev4, ev5); oEp.w = pack2(ev6, ev7);
  agg4[n * 32 + li]      = oXh;    // uints n*128 + 4li..+3 : features 8li..8li+7
  agg4[n * 32 + 16 + li] = oEp;    // uints n*128 + 64+4li  : features 128+8li..+7
}

// ---- MFMA GEMM + bias + ReLU + node-sum (VERBATIM R3/R6, verified) ---------
__global__ __launch_bounds__(256) void k_gemm(const unsigned short* __restrict__ agg,
    const float* __restrict__ W, const float* __restrict__ b,
    float* __restrict__ partials) {
  int tid = threadIdx.x;
  int lane = tid & 63;
  int w = tid >> 6;          // wave -> n-tiles {2w, 2w+1}
  int col = lane & 15;
  int quad = lane >> 4;

  bf16x8 Bsh[2][4];
  bf16x8 Bep[2];
  float bias[2];
#pragma unroll
  for (int i = 0; i < 2; ++i) {
    int obase = (2 * w + i) * 16;
    bias[i] = b[obase + col];
#pragma unroll
    for (int kb = 0; kb < 4; ++kb) {
      bf16x8 f;
#pragma unroll
      for (int j = 0; j < 8; ++j) {
        int k = kb * 32 + quad * 8 + j;
        int wr = (k < 96) ? k : k + 32;            // h block at W rows 128..159
        f[j] = (short)f2bf(W[wr * D_OUTF + obase + col]);
      }
      Bsh[i][kb] = f;
    }
    bf16x8 g;
#pragma unroll
    for (int j = 0; j < 8; ++j)
      g[j] = (short)f2bf(W[(96 + quad * 8 + j) * D_OUTF + obase + col]);
    Bep[i] = g;
  }

  f32x4 psum[4][2];
#pragma unroll
  for (int s = 0; s < 4; ++s)
#pragma unroll
    for (int i = 0; i < 2; ++i) psum[s][i] = (f32x4){0.f, 0.f, 0.f, 0.f};

  for (int t = blockIdx.x; t < NTILES; t += gridDim.x) {
    const unsigned short* arow = agg + (long)(t * 16 + col) * F_PACK;
    bf16x8 Ash[4];
#pragma unroll
    for (int kb = 0; kb < 4; ++kb)
      Ash[kb] = *(const bf16x8*)(arow + kb * 32 + quad * 8);
    f32x4 csh[2];
    csh[0] = (f32x4){0.f, 0.f, 0.f, 0.f};
    csh[1] = (f32x4){0.f, 0.f, 0.f, 0.f};
#pragma unroll
    for (int kb = 0; kb < 4; ++kb) {
      csh[0] = __builtin_amdgcn_mfma_f32_16x16x32_bf16(Ash[kb], Bsh[0][kb], csh[0], 0, 0, 0);
      csh[1] = __builtin_amdgcn_mfma_f32_16x16x32_bf16(Ash[kb], Bsh[1][kb], csh[1], 0, 0, 0);
    }
#pragma unroll
    for (int s = 0; s < 4; ++s) {
      bf16x8 Aep = *(const bf16x8*)(arow + 128 + s * 32 + quad * 8);
#pragma unroll
      for (int i = 0; i < 2; ++i) {
        f32x4 c = __builtin_amdgcn_mfma_f32_16x16x32_bf16(Aep, Bep[i], csh[i], 0, 0, 0);
#pragma unroll
        for (int r = 0; r < 4; ++r)
          psum[s][i][r] += fmaxf(c[r] + bias[i], 0.f);
      }
    }
  }

#pragma unroll
  for (int s = 0; s < 4; ++s)
#pragma unroll
    for (int i = 0; i < 2; ++i) {
      float v = psum[s][i][0] + psum[s][i][1] + psum[s][i][2] + psum[s][i][3];
      v += __shfl_xor(v, 16, 64);
      v += __shfl_xor(v, 32, 64);
      if (quad == 0)
        partials[blockIdx.x * 512 + s * 128 + (2 * w + i) * 16 + col] = v;
    }
}

__global__ void k_reduce(const float* __restrict__ partials, float* __restrict__ means) {
  int idx = blockIdx.x * 64 + threadIdx.x;   // 8 x 64 -> 512
  float t = 0.f;
  for (int blk = 0; blk < GEMM_BLOCKS; ++blk) t += partials[blk * 512 + idx];
  means[idx] = fmaxf(t * (1.0f / (float)N_NODES), 0.f);
}

// ---- broadcast output + epsilon passthrough --------------------------------
#define OUT0_F4 6400000L
#define EPS_F4  1600000L
__global__ void k_out(const float* __restrict__ means, const float* __restrict__ eps,
                      float* __restrict__ out) {
  long i = (long)blockIdx.x * blockDim.x + threadIdx.x;
  if (i < OUT0_F4) {
    int o4 = (int)(i & 31);
    long sn = i >> 5;
    int s = (int)(sn / N_NODES);
    ((float4*)out)[i] = ((const float4*)means)[s * 32 + o4];
  } else if (i < OUT0_F4 + EPS_F4) {
    long j = i - OUT0_F4;
    ((float4*)out)[OUT0_F4 + j] = ((const float4*)eps)[j];
  }
}

extern "C" void kernel_launch(void* const* d_in, const int* in_sizes, int n_in,
                              void* d_out, int out_size, void* d_ws, size_t ws_size,
                              hipStream_t stream) {
  const float* X    = (const float*)d_in[0];
  const float* h    = (const float*)d_in[1];
  const float* eps  = (const float*)d_in[2];
  const float* W    = (const float*)d_in[3];
  const float* b    = (const float*)d_in[4];
  const float* geps = (const float*)d_in[5];
  const int*   src  = (const int*)d_in[6];
  const int*   dst  = (const int*)d_in[7];
  float* out = (float*)d_out;

  char* w = (char*)d_ws;
  unsigned int*  featXH = (unsigned int*)w;  w += (size_t)N_NODES * 64 * 4;   // 12.8 MB
  unsigned int*  epsb   = (unsigned int*)w;  w += (size_t)N_NODES * 4 * 4;    // 0.8 MB
  unsigned int*  agg_u  = (unsigned int*)w;  w += (size_t)N_NODES * 128 * 4;  // 25.6 MB
  int*   off      = (int*)w;   w += (size_t)(N_NODES + 16) * 4;
  int*   cnt      = (int*)w;   w += (size_t)N_NODES * 4;
  int*   cursor   = (int*)w;   w += (size_t)N_NODES * 4;
  int*   csr      = (int*)w;   w += (size_t)N_EDGES * 4;
  int*   bsum     = (int*)w;   w += 256 * 4;
  int*   boff     = (int*)w;   w += 256 * 4;
  float* partials = (float*)w; w += (size_t)GEMM_BLOCKS * 512 * 4;
  float* means    = (float*)w; w += 512 * 4;

  int eb = (N_EDGES + 255) / 256;
  k_pack<<<PB_TOT, 256, 0, stream>>>(X, h, eps, featXH, epsb, cnt);
  k_hist<<<eb, 256, 0, stream>>>(dst, cnt);
  k_scan1<<<NB1, 256, 0, stream>>>(cnt, off, bsum);
  k_scan2<<<1, 256, 0, stream>>>(bsum, boff);
  k_scan3<<<NB1, 256, 0, stream>>>(off, boff, cursor);
  k_scatter<<<eb, 256, 0, stream>>>(src, dst, cursor, csr);

  k_agg16<<<NTILES, 256, 0, stream>>>((const uint4*)featXH, epsb,
                                      geps, off, csr, (uint4*)agg_u);

  k_gemm<<<GEMM_BLOCKS, 256, 0, stream>>>((const unsigned short*)agg_u, W, b, partials);
  k_reduce<<<8, 64, 0, stream>>>(partials, means);

  long total_f4 = OUT0_F4 + EPS_F4;
  k_out<<<(int)((total_f4 + 255) / 256), 256, 0, stream>>>(means, eps, out);
}